// Round 2
// baseline (429.318 us; speedup 1.0000x reference)
//
#include <hip/hip_runtime.h>

// STDP plasticity: out = clip(W + (LR/B) * post^T @ pre, 0, 1)
// W: [8192 x 8192] fp32, pre/post: [32 x 8192] fp32.
// Memory-bound streaming kernel: 256 MB W-read + 256 MB out-write.
//
// R4: no-LDS. pre (1 MB) and post (1 MB) are fully L2-resident, so LDS
// staging was pure overhead (guide common-mistake #7): a stage+sync
// convoy per block round, plus ~12 cyc/dense ds_read_b128 of LDS-unit
// occupancy that serialized against the HBM stream (R3 did 128 dense
// LDS reads/thread). Now:
//  - p: dense float4 global load per batch iter, L2-hit (~512 MB L2
//    traffic over kernel lifetime ~= 7 TB/s, well under 34.5 TB/s L2).
//  - q: wave-uniform post row via readfirstlane-scalarized pointer ->
//    s_load path (scalar cache, off the vector-memory pipe).
//  - No barriers anywhere: waves drift out of phase, so HBM read/write
//    (W/out) traffic from epilogue-phase waves overlaps compute-phase
//    waves structurally. 4-row early W prefetch starts the HBM read
//    stream at t=0.
// Occupancy: LDS=0; VGPR ~ acc(64)+w0(16)+pipeline(~30) -> <=128,
// 4 waves/SIMD.

#define DIM    8192
#define BATCH  32
#define SCALE  (0.01f / 32.0f)   // LR / B

#define BTO 64    // block tile rows (o): 4 waves x 16
#define BTI 256   // block tile cols (i): 64 lanes x 4

typedef __attribute__((ext_vector_type(4))) float f4;

__global__ __launch_bounds__(256) void stdp_update_kernel(
    const float* __restrict__ W,
    const float* __restrict__ pre,
    const float* __restrict__ post,
    float* __restrict__ out)
{
    const int tid = threadIdx.x;
    const int i0  = blockIdx.x * BTI;
    const int o0  = blockIdx.y * BTO;

    const int ci = (tid & 63) << 2;   // i offset: one float4 per lane, dense across wave
    const int og = (tid >> 6) << 4;   // o offset: 16 rows per wave (wave-uniform)

    // This lane's base element: row (o0+og), col (i0+ci).
    const size_t base = (size_t)(o0 + og) * DIM + i0 + ci;

    // Early W prefetch (rows 0-3): HBM read stream starts at t=0.
    // 64 lanes x 16 B = 1 KB dense per instruction.
    f4 w0[4];
    #pragma unroll
    for (int r = 0; r < 4; ++r)
        w0[r] = __builtin_nontemporal_load((const f4*)(W + base + (size_t)r * DIM));

    // Wave-uniform post-row base: readfirstlane pins it in SGPRs so the
    // 16 q loads per batch-iter go down the scalar (s_load) path.
    const int orow = __builtin_amdgcn_readfirstlane(o0 + og);
    const float* __restrict__ prow = post + orow;
    const float* __restrict__ pcol = pre + i0 + ci;

    float acc[16][4];
    #pragma unroll
    for (int r = 0; r < 16; ++r)
        #pragma unroll
        for (int c = 0; c < 4; ++c)
            acc[r][c] = 0.0f;

    #pragma unroll 4
    for (int b = 0; b < BATCH; ++b) {
        const f4 p = *(const f4*)(pcol + (size_t)b * DIM);   // dense, L2-hit
        float q[16];                                          // wave-uniform
        *(f4*)&q[0]  = *(const f4*)(prow + (size_t)b * DIM + 0);
        *(f4*)&q[4]  = *(const f4*)(prow + (size_t)b * DIM + 4);
        *(f4*)&q[8]  = *(const f4*)(prow + (size_t)b * DIM + 8);
        *(f4*)&q[12] = *(const f4*)(prow + (size_t)b * DIM + 12);
        #pragma unroll
        for (int r = 0; r < 16; ++r)
            #pragma unroll
            for (int c = 0; c < 4; ++c)
                acc[r][c] = fmaf(q[r], p[c], acc[r][c]);
    }

    // Epilogue. Rows 0-3 use the early prefetch; rows 4-15 load+store in
    // 4-row groups (unrolled; compiler pipelines the loads ahead).
    // Every load/store: 64 lanes x 16 B contiguous = 1 KB dense.
    #pragma unroll
    for (int r = 0; r < 4; ++r) {
        const size_t off = base + (size_t)r * DIM;
        f4 r4;
        r4.x = fminf(fmaxf(fmaf(SCALE, acc[r][0], w0[r].x), 0.0f), 1.0f);
        r4.y = fminf(fmaxf(fmaf(SCALE, acc[r][1], w0[r].y), 0.0f), 1.0f);
        r4.z = fminf(fmaxf(fmaf(SCALE, acc[r][2], w0[r].z), 0.0f), 1.0f);
        r4.w = fminf(fmaxf(fmaf(SCALE, acc[r][3], w0[r].w), 0.0f), 1.0f);
        __builtin_nontemporal_store(r4, (f4*)(out + off));
    }

    #pragma unroll
    for (int g = 1; g < 4; ++g) {
        f4 w[4];
        #pragma unroll
        for (int r = 0; r < 4; ++r)
            w[r] = __builtin_nontemporal_load(
                (const f4*)(W + base + (size_t)(g * 4 + r) * DIM));
        #pragma unroll
        for (int r = 0; r < 4; ++r) {
            const int  row = g * 4 + r;
            const size_t off = base + (size_t)row * DIM;
            f4 r4;
            r4.x = fminf(fmaxf(fmaf(SCALE, acc[row][0], w[r].x), 0.0f), 1.0f);
            r4.y = fminf(fmaxf(fmaf(SCALE, acc[row][1], w[r].y), 0.0f), 1.0f);
            r4.z = fminf(fmaxf(fmaf(SCALE, acc[row][2], w[r].z), 0.0f), 1.0f);
            r4.w = fminf(fmaxf(fmaf(SCALE, acc[row][3], w[r].w), 0.0f), 1.0f);
            __builtin_nontemporal_store(r4, (f4*)(out + off));
        }
    }
}

extern "C" void kernel_launch(void* const* d_in, const int* in_sizes, int n_in,
                              void* d_out, int out_size, void* d_ws, size_t ws_size,
                              hipStream_t stream) {
    const float* W    = (const float*)d_in[0];
    const float* pre  = (const float*)d_in[1];
    const float* post = (const float*)d_in[2];
    float*       out  = (float*)d_out;

    dim3 grid(DIM / BTI, DIM / BTO);   // 32 x 128 = 4096 blocks
    stdp_update_kernel<<<grid, 256, 0, stream>>>(W, pre, post, out);
}